// Round 4
// baseline (228.529 us; speedup 1.0000x reference)
//
#include <hip/hip_runtime.h>
#include <hip/hip_bf16.h>

#define BSZ 256
#define ADIM 128
#define HID 512
#define MT 128         // pair-rows per block
#define LDH 520        // padded LDS row stride in bf16 elements

typedef __attribute__((ext_vector_type(8))) short short8;
typedef __attribute__((ext_vector_type(4))) float float4_t;

__device__ inline short f32_to_bf16_bits(float f) {
    union { float f; unsigned u; } v; v.f = f;
    unsigned u = v.u;
    unsigned r = u + 0x7FFFu + ((u >> 16) & 1u);   // RNE
    return (short)(r >> 16);
}
__device__ inline float bf16_bits_to_f32(short s) {
    union { unsigned u; float f; } v;
    v.u = ((unsigned)(unsigned short)s) << 16;
    return v.f;
}

// ---------------- prep (256 blocks x 512 threads) ----------------
__global__ __launch_bounds__(512) void prep_kernel(
        const float* __restrict__ x, const float* __restrict__ y,
        const float* __restrict__ Wx, const float* __restrict__ Wy,
        const float* __restrict__ b0, const float* __restrict__ W1,
        const float* __restrict__ W2,
        float* __restrict__ hx, float* __restrict__ hy,
        short* __restrict__ W1t, short* __restrict__ W2t) {
    __shared__ float lds[64 * 65];
    const int tid = threadIdx.x;
    const int bid = blockIdx.x;

    if (bid < 128) {
        const bool isX = bid < 64;
        const int i0 = (isX ? bid : bid - 64) * 4;
        const float* src = isX ? x : y;
        const float* W   = isX ? Wx : Wy;
        float* dst       = isX ? hx : hy;

        lds[tid] = src[i0 * ADIM + tid];
        __syncthreads();

        const int h = tid;
        float s0 = 0.f, s1 = 0.f, s2 = 0.f, s3 = 0.f;
        const float* wcol = W + h;
        #pragma unroll 8
        for (int k = 0; k < ADIM; ++k) {
            float w = wcol[k * HID];
            s0 = fmaf(lds[k], w, s0);
            s1 = fmaf(lds[ADIM + k], w, s1);
            s2 = fmaf(lds[2 * ADIM + k], w, s2);
            s3 = fmaf(lds[3 * ADIM + k], w, s3);
        }
        float bb = isX ? b0[h] : 0.f;
        dst[(i0 + 0) * HID + h] = s0 + bb;
        dst[(i0 + 1) * HID + h] = s1 + bb;
        dst[(i0 + 2) * HID + h] = s2 + bb;
        dst[(i0 + 3) * HID + h] = s3 + bb;
    } else {
        const int tb = bid - 128;
        const bool is1 = tb < 64;
        const int t8 = is1 ? tb : tb - 64;
        const float* Wsrc = is1 ? W1 : W2;
        short* Wdst = is1 ? W1t : W2t;
        const int k0 = (t8 >> 3) * 64;
        const int n0 = (t8 & 7) * 64;

        #pragma unroll
        for (int i = 0; i < 8; ++i) {
            int r = (tid >> 6) + i * 8;
            int c = tid & 63;
            lds[c * 65 + r] = Wsrc[(k0 + r) * HID + n0 + c];
        }
        __syncthreads();
        #pragma unroll
        for (int i = 0; i < 8; ++i) {
            int n = (tid >> 6) + i * 8;
            int k = tid & 63;
            Wdst[(n0 + n) * HID + k0 + k] = f32_to_bf16_bits(lds[n * 65 + k]);
        }
    }
}

// ---------------- fused layer: wave computes 64(M) x 128(N) chunk ----------------
// A (h) from LDS, W (transposed [N][K]) from global with depth-1 B double-buffer.
// Single hs buffer: compute -> barrier -> overwrite with relu(bf16) -> barrier.
__device__ __forceinline__ void gemm_layer(short* __restrict__ hs,
                                           const short* __restrict__ Wt,
                                           const float* __restrict__ bias,
                                           int wm, int wn, int lane) {
    const int quad = lane >> 4;
    const int lq = lane & 15;

    float4_t acc[4][8];
    #pragma unroll
    for (int mi = 0; mi < 4; ++mi)
        #pragma unroll
        for (int ni = 0; ni < 8; ++ni)
            acc[mi][ni] = (float4_t){0.f, 0.f, 0.f, 0.f};

    const short* abase = hs + (wm * 64 + lq) * LDH + quad * 8;
    const short* wbase = Wt + (wn * 128 + lq) * HID + quad * 8;

    short8 bf[2][8];
    #pragma unroll
    for (int ni = 0; ni < 8; ++ni)
        bf[0][ni] = *(const short8*)(wbase + ni * 16 * HID);

    #pragma unroll
    for (int s = 0; s < 16; ++s) {
        const int cur = s & 1;
        const int nxt = cur ^ 1;
        if (s < 15) {
            #pragma unroll
            for (int ni = 0; ni < 8; ++ni)
                bf[nxt][ni] = *(const short8*)(wbase + ni * 16 * HID + (s + 1) * 32);
        }
        short8 af[4];
        #pragma unroll
        for (int mi = 0; mi < 4; ++mi)
            af[mi] = *(const short8*)(abase + mi * 16 * LDH + s * 32);
        #pragma unroll
        for (int mi = 0; mi < 4; ++mi)
            #pragma unroll
            for (int ni = 0; ni < 8; ++ni)
                acc[mi][ni] = __builtin_amdgcn_mfma_f32_16x16x32_bf16(
                    af[mi], bf[cur][ni], acc[mi][ni], 0, 0, 0);
    }

    float bv[8];
    #pragma unroll
    for (int ni = 0; ni < 8; ++ni) bv[ni] = bias[wn * 128 + ni * 16 + lq];

    __syncthreads();   // all reads of hs complete before overwrite

    #pragma unroll
    for (int mi = 0; mi < 4; ++mi)
        #pragma unroll
        for (int ni = 0; ni < 8; ++ni)
            #pragma unroll
            for (int r = 0; r < 4; ++r) {
                float v = acc[mi][ni][r] + bv[ni];
                v = fmaxf(v, 0.f);
                hs[(wm * 64 + mi * 16 + quad * 4 + r) * LDH + wn * 128 + ni * 16 + lq]
                    = f32_to_bf16_bits(v);
            }
    __syncthreads();
}

__global__ __launch_bounds__(512, 2) void critic_kernel(
    const float* __restrict__ hx, const float* __restrict__ hy,
    const short* __restrict__ W1t, const short* __restrict__ W2t,
    const float* __restrict__ b1, const float* __restrict__ b2,
    const float* __restrict__ W3, const float* __restrict__ b3,
    float* __restrict__ out) {
    __shared__ short hs[MT * LDH];   // 133,120 B
    __shared__ float psum[512];      // 2,048 B  (total 135,168 -> 1 block/CU)

    const int tid = threadIdx.x;
    const int wave = tid >> 6;
    const int lane = tid & 63;
    const int wm = wave >> 2;        // 0..1  (M half)
    const int wn = wave & 3;         // 0..3  (N quarter)

    const int i0 = (blockIdx.x >> 5) * 16;   // 16 i-rows per block
    const int j0 = (blockIdx.x & 31) * 8;    // 8 j-rows per block

    // ---- h0 = relu(hx[i] + hy[j]) bf16 in LDS (b0 folded into hx) ----
    #pragma unroll 4
    for (int e = tid; e < MT * 64; e += 512) {
        int r = e >> 6;              // pair-row 0..127
        int ko = (e & 63) * 8;       // 8-elem chunk
        int ti = r >> 3, tj = r & 7;
        const float4_t* px = (const float4_t*)(hx + (i0 + ti) * HID + ko);
        const float4_t* py = (const float4_t*)(hy + (j0 + tj) * HID + ko);
        float4_t a0 = px[0], a1 = px[1];
        float4_t c0 = py[0], c1 = py[1];
        short8 v;
        #pragma unroll
        for (int u = 0; u < 4; ++u) v[u]     = f32_to_bf16_bits(fmaxf(a0[u] + c0[u], 0.f));
        #pragma unroll
        for (int u = 0; u < 4; ++u) v[4 + u] = f32_to_bf16_bits(fmaxf(a1[u] + c1[u], 0.f));
        *(short8*)(hs + r * LDH + ko) = v;
    }
    __syncthreads();

    gemm_layer(hs, W1t, b1, wm, wn, lane);   // h1 = relu(h0 @ W1 + b1)
    gemm_layer(hs, W2t, b2, wm, wn, lane);   // h2 = relu(h1 @ W2 + b2)

    // ---- final: out = h2 @ W3 + b3 ----
    {
        int r = tid >> 2;            // row 0..127
        int oc = (tid & 3) * 128;    // k chunk of 128
        const short* hrow = hs + r * LDH + oc;
        float s = 0.f;
        #pragma unroll
        for (int k = 0; k < 128; k += 8) {
            short8 v = *(const short8*)(hrow + k);
            #pragma unroll
            for (int u = 0; u < 8; ++u)
                s = fmaf(bf16_bits_to_f32(v[u]), W3[oc + k + u], s);
        }
        psum[tid] = s;
    }
    __syncthreads();
    if (tid < 128) {
        float s = b3[0] + psum[tid * 4] + psum[tid * 4 + 1]
                        + psum[tid * 4 + 2] + psum[tid * 4 + 3];
        out[(i0 + (tid >> 3)) * BSZ + j0 + (tid & 7)] = s;
    }
}

extern "C" void kernel_launch(void* const* d_in, const int* in_sizes, int n_in,
                              void* d_out, int out_size, void* d_ws, size_t ws_size,
                              hipStream_t stream) {
    const float* x  = (const float*)d_in[0];
    const float* y  = (const float*)d_in[1];
    const float* Wx = (const float*)d_in[2];
    const float* Wy = (const float*)d_in[3];
    const float* b0 = (const float*)d_in[4];
    const float* W1 = (const float*)d_in[5];
    const float* b1 = (const float*)d_in[6];
    const float* W2 = (const float*)d_in[7];
    const float* b2 = (const float*)d_in[8];
    const float* W3 = (const float*)d_in[9];
    const float* b3 = (const float*)d_in[10];
    float* out = (float*)d_out;

    char* ws = (char*)d_ws;
    float* hx  = (float*)(ws);
    float* hy  = (float*)(ws + 512 * 1024);
    short* W1t = (short*)(ws + 1024 * 1024);
    short* W2t = (short*)(ws + 1536 * 1024);

    prep_kernel<<<256, 512, 0, stream>>>(x, y, Wx, Wy, b0, W1, W2, hx, hy, W1t, W2t);
    critic_kernel<<<512, 512, 0, stream>>>(hx, hy, W1t, W2t, b1, b2, W3, b3, out);
}

// Round 5
// 147.030 us; speedup vs baseline: 1.5543x; 1.5543x over previous
//
#include <hip/hip_runtime.h>
#include <hip/hip_bf16.h>

#define BSZ 256
#define ADIM 128
#define HID 512
#define MT 64          // pair-rows per block
#define LDH 520        // padded LDS row stride in bf16 elements

typedef __attribute__((ext_vector_type(8))) short short8;
typedef __attribute__((ext_vector_type(4))) float float4_t;

__device__ inline short f32_to_bf16_bits(float f) {
    union { float f; unsigned u; } v; v.f = f;
    unsigned u = v.u;
    unsigned r = u + 0x7FFFu + ((u >> 16) & 1u);   // RNE
    return (short)(r >> 16);
}
__device__ inline float bf16_bits_to_f32(short s) {
    union { unsigned u; float f; } v;
    v.u = ((unsigned)(unsigned short)s) << 16;
    return v.f;
}

// ---------------- prep (256 blocks x 512 threads) ----------------
// blocks [0,64):    hx = x@Wx + b0   (4 rows per block)
// blocks [64,128):  hy = y@Wy        (4 rows per block)
// blocks [128,192): W1p = fragment-packed bf16 of W1 (64x64 tile per block)
// blocks [192,256): W2p = fragment-packed bf16 of W2
// Packed layout: Wp[((s*32+g)*64 + lane)*8 + j] = W[s*32 + (lane>>4)*8 + j][g*16 + (lane&15)]
// so the main kernel's B-fragment load is base + lane*16B, fully coalesced.
__global__ __launch_bounds__(512) void prep_kernel(
        const float* __restrict__ x, const float* __restrict__ y,
        const float* __restrict__ Wx, const float* __restrict__ Wy,
        const float* __restrict__ b0, const float* __restrict__ W1,
        const float* __restrict__ W2,
        float* __restrict__ hx, float* __restrict__ hy,
        short* __restrict__ W1p, short* __restrict__ W2p) {
    __shared__ float lds[64 * 65];
    const int tid = threadIdx.x;
    const int bid = blockIdx.x;

    if (bid < 128) {
        const bool isX = bid < 64;
        const int i0 = (isX ? bid : bid - 64) * 4;
        const float* src = isX ? x : y;
        const float* W   = isX ? Wx : Wy;
        float* dst       = isX ? hx : hy;

        lds[tid] = src[i0 * ADIM + tid];
        __syncthreads();

        const int h = tid;
        float s0 = 0.f, s1 = 0.f, s2 = 0.f, s3 = 0.f;
        const float* wcol = W + h;
        #pragma unroll 8
        for (int k = 0; k < ADIM; ++k) {
            float w = wcol[k * HID];
            s0 = fmaf(lds[k], w, s0);
            s1 = fmaf(lds[ADIM + k], w, s1);
            s2 = fmaf(lds[2 * ADIM + k], w, s2);
            s3 = fmaf(lds[3 * ADIM + k], w, s3);
        }
        float bb = isX ? b0[h] : 0.f;
        dst[(i0 + 0) * HID + h] = s0 + bb;
        dst[(i0 + 1) * HID + h] = s1 + bb;
        dst[(i0 + 2) * HID + h] = s2 + bb;
        dst[(i0 + 3) * HID + h] = s3 + bb;
    } else {
        const int tb = bid - 128;
        const bool is1 = tb < 64;
        const int t8 = is1 ? tb : tb - 64;
        const float* Wsrc = is1 ? W1 : W2;
        short* Wdst = is1 ? W1p : W2p;
        const int k0 = (t8 >> 3) * 64;      // source k block
        const int n0 = (t8 & 7) * 64;       // source n block

        // load + transpose 64x64 f32 tile into LDS: lds[n*65 + k]
        #pragma unroll
        for (int i = 0; i < 8; ++i) {
            int r = (tid >> 6) + i * 8;     // k within tile
            int c = tid & 63;               // n within tile (coalesced)
            lds[c * 65 + r] = Wsrc[(k0 + r) * HID + n0 + c];
        }
        __syncthreads();

        // write fragment-packed: thread t -> one 16B chunk
        const int local_s = tid >> 8;           // 0..1  (k-slice of 32 within tile)
        const int g_local = (tid >> 6) & 3;     // 0..3  (n-group of 16 within tile)
        const int lane    = tid & 63;
        const int quad    = lane >> 4;
        const int lq      = lane & 15;
        const int s_glob  = (t8 >> 3) * 2 + local_s;   // 0..15
        const int g_glob  = (t8 & 7) * 4 + g_local;    // 0..31

        const float* srcp = lds + (g_local * 16 + lq) * 65 + local_s * 32 + quad * 8;
        short8 v;
        #pragma unroll
        for (int j = 0; j < 8; ++j) v[j] = f32_to_bf16_bits(srcp[j]);
        *(short8*)(Wdst + ((s_glob * 32 + g_glob) * 64 + lane) * 8) = v;
    }
}

// ---------------- fused layer: wave computes 64(M) x 64(N) chunk ----------------
// A (h) from LDS; B from fragment-packed global (coalesced b128, depth-1 dbuf).
// Single hs buffer: compute -> barrier -> overwrite with relu(bf16) -> barrier.
__device__ __forceinline__ void gemm_layer(short* __restrict__ hs,
                                           const short* __restrict__ Wp,
                                           const float* __restrict__ bias,
                                           int wave, int lane) {
    const int quad = lane >> 4;
    const int lq = lane & 15;
    const int n0 = wave * 64;

    float4_t acc[4][4];
    #pragma unroll
    for (int mi = 0; mi < 4; ++mi)
        #pragma unroll
        for (int ni = 0; ni < 4; ++ni)
            acc[mi][ni] = (float4_t){0.f, 0.f, 0.f, 0.f};

    // fragment-packed base for this wave: groups g = wave*4 + ni
    const short* pb = Wp + wave * 2048 + lane * 8;     // + ni*512 + s*16384
    const short* abase = hs + lq * LDH + quad * 8;

    short8 bf[2][4];
    #pragma unroll
    for (int ni = 0; ni < 4; ++ni)
        bf[0][ni] = *(const short8*)(pb + ni * 512);

    #pragma unroll
    for (int s = 0; s < 16; ++s) {
        const int cur = s & 1;
        if (s < 15) {
            #pragma unroll
            for (int ni = 0; ni < 4; ++ni)
                bf[cur ^ 1][ni] = *(const short8*)(pb + (s + 1) * 16384 + ni * 512);
        }
        short8 af[4];
        #pragma unroll
        for (int mi = 0; mi < 4; ++mi)
            af[mi] = *(const short8*)(abase + mi * 16 * LDH + s * 32);
        #pragma unroll
        for (int mi = 0; mi < 4; ++mi)
            #pragma unroll
            for (int ni = 0; ni < 4; ++ni)
                acc[mi][ni] = __builtin_amdgcn_mfma_f32_16x16x32_bf16(
                    af[mi], bf[cur][ni], acc[mi][ni], 0, 0, 0);
    }

    float bv[4];
    #pragma unroll
    for (int ni = 0; ni < 4; ++ni) bv[ni] = bias[n0 + ni * 16 + lq];

    __syncthreads();   // all reads of hs complete before overwrite

    #pragma unroll
    for (int ni = 0; ni < 4; ++ni) {
        #pragma unroll
        for (int mi = 0; mi < 4; ++mi) {
            #pragma unroll
            for (int r = 0; r < 4; ++r) {
                float v = acc[mi][ni][r] + bv[ni];
                v = fmaxf(v, 0.f);
                hs[(mi * 16 + quad * 4 + r) * LDH + n0 + ni * 16 + lq] = f32_to_bf16_bits(v);
            }
        }
    }
    __syncthreads();
}

__global__ __launch_bounds__(512, 4) void critic_kernel(
    const float* __restrict__ hx, const float* __restrict__ hy,
    const short* __restrict__ W1p, const short* __restrict__ W2p,
    const float* __restrict__ b1, const float* __restrict__ b2,
    const float* __restrict__ W3, const float* __restrict__ b3,
    float* __restrict__ out) {
    __shared__ short hs[MT * LDH];   // 66,560 B
    __shared__ float psum[512];      // 2,048 B  (total 68,608 -> 2 blocks/CU)

    const int tid = threadIdx.x;
    const int wave = tid >> 6;
    const int lane = tid & 63;

    const int i0 = (blockIdx.x >> 5) * 8;
    const int j0 = (blockIdx.x & 31) * 8;

    // ---- h0 = relu(hx[i] + hy[j]) bf16 in LDS (b0 folded into hx) ----
    #pragma unroll
    for (int e = tid; e < MT * 64; e += 512) {
        int r = e >> 6;
        int ko = (e & 63) * 8;
        int ti = r >> 3, tj = r & 7;
        const float4_t* px = (const float4_t*)(hx + (i0 + ti) * HID + ko);
        const float4_t* py = (const float4_t*)(hy + (j0 + tj) * HID + ko);
        float4_t a0 = px[0], a1 = px[1];
        float4_t c0 = py[0], c1 = py[1];
        short8 v;
        #pragma unroll
        for (int u = 0; u < 4; ++u) v[u]     = f32_to_bf16_bits(fmaxf(a0[u] + c0[u], 0.f));
        #pragma unroll
        for (int u = 0; u < 4; ++u) v[4 + u] = f32_to_bf16_bits(fmaxf(a1[u] + c1[u], 0.f));
        *(short8*)(hs + r * LDH + ko) = v;
    }
    __syncthreads();

    gemm_layer(hs, W1p, b1, wave, lane);   // h1 = relu(h0 @ W1 + b1)
    gemm_layer(hs, W2p, b2, wave, lane);   // h2 = relu(h1 @ W2 + b2)

    // ---- final: out = h2 @ W3 + b3 ----
    {
        int r = tid >> 3;
        int oc = (tid & 7) * 64;
        const short* hrow = hs + r * LDH + oc;
        float s = 0.f;
        #pragma unroll
        for (int k = 0; k < 64; k += 8) {
            short8 v = *(const short8*)(hrow + k);
            #pragma unroll
            for (int u = 0; u < 8; ++u)
                s = fmaf(bf16_bits_to_f32(v[u]), W3[oc + k + u], s);
        }
        psum[tid] = s;
    }
    __syncthreads();
    if (tid < 64) {
        float s = b3[0];
        #pragma unroll
        for (int o = 0; o < 8; ++o) s += psum[tid * 8 + o];
        int ti = tid >> 3, tj = tid & 7;
        out[(i0 + ti) * BSZ + (j0 + tj)] = s;
    }
}

extern "C" void kernel_launch(void* const* d_in, const int* in_sizes, int n_in,
                              void* d_out, int out_size, void* d_ws, size_t ws_size,
                              hipStream_t stream) {
    const float* x  = (const float*)d_in[0];
    const float* y  = (const float*)d_in[1];
    const float* Wx = (const float*)d_in[2];
    const float* Wy = (const float*)d_in[3];
    const float* b0 = (const float*)d_in[4];
    const float* W1 = (const float*)d_in[5];
    const float* b1 = (const float*)d_in[6];
    const float* W2 = (const float*)d_in[7];
    const float* b2 = (const float*)d_in[8];
    const float* W3 = (const float*)d_in[9];
    const float* b3 = (const float*)d_in[10];
    float* out = (float*)d_out;

    char* ws = (char*)d_ws;
    float* hx  = (float*)(ws);
    float* hy  = (float*)(ws + 512 * 1024);
    short* W1p = (short*)(ws + 1024 * 1024);
    short* W2p = (short*)(ws + 1536 * 1024);

    prep_kernel<<<256, 512, 0, stream>>>(x, y, Wx, Wy, b0, W1, W2, hx, hy, W1p, W2p);
    critic_kernel<<<1024, 512, 0, stream>>>(hx, hy, W1p, W2p, b1, b2, W3, b3, out);
}